// Round 8
// baseline (202.056 us; speedup 1.0000x reference)
//
#include <hip/hip_runtime.h>

#define N_IN  1024
#define N_OUT 512
#define BATCH 128
#define M     (N_IN + 1)     // 1025 word lines (weights + bias line)

// ws layout: cnt (unsigned) at offset 0; maxp[1024] floats at offset 256
#define WS_CNT_OFF  0
#define WS_MAXP_OFF 256

#define CH   32
#define IC   32
#define NBLK 1024            // 8 jt * 4 bt * 32 ic ; = 4 blocks/CU * 256 CU

// fast base-2 transcendentals: v_exp_f32 / v_log_f32 (both base-2 on AMDGPU)
#if defined(__has_builtin)
#  if __has_builtin(__builtin_amdgcn_exp2f)
#    define FAST_EXP2(x) __builtin_amdgcn_exp2f(x)
#  endif
#  if __has_builtin(__builtin_amdgcn_logf)
#    define FAST_LOG2(x) __builtin_amdgcn_logf(x)
#  endif
#endif
#ifndef FAST_EXP2
#  define FAST_EXP2(x) exp2f(x)
#endif
#ifndef FAST_LOG2
#  define FAST_LOG2(x) log2f(x)
#endif

// ---------------------------------------------------------------------------
// Fused single-dispatch kernel (cooperative launch, all 1024 blocks resident).
// Phase 0 (pre-barrier): zero y slice; stage (l,s) of x-tile into LDS; scan
//   own 32x64 weight tile for max|w| (doubles as L2 prefetch); partial ->
//   maxp[bid] via device-scope atomicExch.
// Grid barrier: counter in ws (memset to 0 before launch).
// Phase 1: reduce 1024 partials -> gofs; main loop identical to round 7:
//   y[b,j] += s * ( exp2(fma(ep,l,lgp)) - exp2(fma(en,l,lgn)) )
// Bias word line handled closed-form by ic==31 blocks (exp2(e*1) = n).
// ---------------------------------------------------------------------------
__global__ __launch_bounds__(256, 4)
void memristor_fused(const float* __restrict__ x,  const float* __restrict__ wp,
                     const float* __restrict__ wn, const float* __restrict__ bp,
                     const float* __restrict__ bn, const float* __restrict__ nn,
                     unsigned* __restrict__ cnt,   float* __restrict__ maxp,
                     float* __restrict__ y)
{
    // [row ii][batch-pair 0..15, +1 pad]; float4 q holds batches (2q, 2q+1)
    __shared__ float4 lsq[CH][17];
    __shared__ float  wred[4];

    const int tid   = threadIdx.x;
    const int jlane = tid & 63;
    const int bid   = blockIdx.x;
    const int jt    = bid & 7;
    const int bt    = (bid >> 3) & 3;
    const int ic    = bid >> 5;                   // 0..31

    const int i0 = ic * CH;
    const int j  = jt * 64 + jlane;
    const int b0 = bt * 32;

    // ---- phase 0a: zero my 64-element slice of y (65536 / 1024 blocks) ----
    if (tid < 64) y[bid * 64 + tid] = 0.0f;

    // ---- phase 0b: stage (l = log2(2|x|), s = sign) 32 batches x 32 rows ----
    {
        const int ii = tid & 31;                  // row in chunk (coalesced x)
        const int b8 = tid >> 5;                  // 0..7
        #pragma unroll
        for (int r = 0; r < 4; ++r) {
            const int bb = b8 + r * 8;            // batch in tile
            const float v = x[(b0 + bb) * N_IN + i0 + ii];
            const float s = (v > 0.0f) ? 1.0f : ((v < 0.0f) ? -1.0f : 0.0f);
            const float l = FAST_LOG2(2.0f * fabsf(v));   // -inf at 0 -> exp2=0
            reinterpret_cast<float2*>(&lsq[ii][0])[bb] = make_float2(l, s);
        }
    }

    // ---- phase 0c: max|w| over OWN weight tile (prefetches L2 for phase 1) --
    const float* wprow = wp + (size_t)i0 * N_OUT + j;
    const float* wnrow = wn + (size_t)i0 * N_OUT + j;
    float m = 0.0f;
    #pragma unroll 8
    for (int ii = 0; ii < CH; ++ii)
        m = fmaxf(m, fmaxf(fabsf(wprow[ii * N_OUT]), fabsf(wnrow[ii * N_OUT])));
    if (ic == IC - 1)                             // bias vectors (all j via jt)
        m = fmaxf(m, fmaxf(fabsf(bp[j]), fabsf(bn[j])));
    #pragma unroll
    for (int off = 32; off > 0; off >>= 1)
        m = fmaxf(m, __shfl_xor(m, off, 64));
    if ((tid & 63) == 0) wred[tid >> 6] = m;
    __syncthreads();
    if (tid == 0) {
        const float bm = fmaxf(fmaxf(wred[0], wred[1]), fmaxf(wred[2], wred[3]));
        atomicExch(&maxp[bid], bm);               // device-scope store
        __threadfence();
        atomicAdd(cnt, 1u);
        // spin until all 1024 blocks arrived (co-resident: cooperative launch)
        while (__hip_atomic_load(cnt, __ATOMIC_RELAXED,
                                 __HIP_MEMORY_SCOPE_AGENT) < NBLK)
            __builtin_amdgcn_s_sleep(1);
    }
    __syncthreads();

    // ---- phase 1a: global max from 1024 partials (16 per lane) ----
    float gm = 0.0f;
    #pragma unroll
    for (int r = 0; r < 16; ++r)
        gm = fmaxf(gm, __hip_atomic_load(&maxp[jlane + r * 64], __ATOMIC_RELAXED,
                                         __HIP_MEMORY_SCOPE_AGENT));
    #pragma unroll
    for (int off = 32; off > 0; off >>= 1)
        gm = fmaxf(gm, __shfl_xor(gm, off, 64));
    const float gofs = 0.125f * __uint_as_float(
        __builtin_amdgcn_readfirstlane(__float_as_uint(gm)));

    const int bslot = __builtin_amdgcn_readfirstlane(tid >> 6);

    float acc[8];
    #pragma unroll
    for (int k = 0; k < 8; ++k) acc[k] = 0.0f;

    const float2* nnrow = (const float2*)nn + (size_t)i0 * N_OUT + j;

    // ---- phase 1b: main loop (weights now L2-warm) ----
    #pragma unroll 2
    for (int ii = 0; ii < CH; ++ii) {
        const float wpv  = wprow[ii * N_OUT];
        const float wnv  = wnrow[ii * N_OUT];
        const float2 np2 = nnrow[ii * N_OUT];
        const float ep  = FAST_LOG2(fmaf(0.2f, np2.x, 2.8f));
        const float en  = FAST_LOG2(fmaf(0.2f, np2.y, 2.8f));
        const float lgp = FAST_LOG2(fmaf(0.5f, wpv, gofs));
        const float lgn = FAST_LOG2(fmaf(0.5f, wnv, gofs));
        #pragma unroll
        for (int mm = 0; mm < 4; ++mm) {
            const float4 q = lsq[ii][bslot * 4 + mm];   // uniform addr: broadcast
            const float Ep0 = FAST_EXP2(fmaf(ep, q.x, lgp));
            const float En0 = FAST_EXP2(fmaf(en, q.x, lgn));
            acc[2 * mm]     = fmaf(q.y, Ep0 - En0, acc[2 * mm]);
            const float Ep1 = FAST_EXP2(fmaf(ep, q.z, lgp));
            const float En1 = FAST_EXP2(fmaf(en, q.z, lgn));
            acc[2 * mm + 1] = fmaf(q.w, Ep1 - En1, acc[2 * mm + 1]);
        }
    }

    // ---- bias word line (i = N_IN): l = 1, s = 1 -> g * n exactly ----
    if (ic == IC - 1) {
        const float2 np2 = ((const float2*)nn)[(size_t)N_IN * N_OUT + j];
        const float npp = fmaf(0.2f, np2.x, 2.8f);
        const float npn = fmaf(0.2f, np2.y, 2.8f);
        const float gp = fmaf(0.5f, bp[j], gofs);
        const float gn = fmaf(0.5f, bn[j], gofs);
        const float t  = fmaf(gp, npp, -(gn * npn));
        #pragma unroll
        for (int k = 0; k < 8; ++k) acc[k] += t;
    }

    #pragma unroll
    for (int k = 0; k < 8; ++k)
        atomicAdd(&y[(b0 + bslot * 8 + k) * N_OUT + j], acc[k]);
}

// ---------------------------------------------------------------------------
// Fallback two-kernel path (round-7, known-good) if cooperative launch fails.
// ---------------------------------------------------------------------------
__global__ __launch_bounds__(256)
void maxred_kernel(const float4* __restrict__ wp4, const float4* __restrict__ wn4,
                   const float* __restrict__ bp, const float* __restrict__ bn,
                   float* __restrict__ maxp, float* __restrict__ y)
{
    const int bid = blockIdx.x;
    const int t   = threadIdx.x;
    y[bid * 256 + t] = 0.0f;
    const int base = bid * 512;
    float m = 0.0f;
    #pragma unroll
    for (int r = 0; r < 2; ++r) {
        const float4 a = wp4[base + r * 256 + t];
        const float4 b = wn4[base + r * 256 + t];
        m = fmaxf(m, fmaxf(fmaxf(fabsf(a.x), fabsf(a.y)),
                           fmaxf(fabsf(a.z), fabsf(a.w))));
        m = fmaxf(m, fmaxf(fmaxf(fabsf(b.x), fabsf(b.y)),
                           fmaxf(fabsf(b.z), fabsf(b.w))));
    }
    if (bid == 0) {
        m = fmaxf(m, fmaxf(fabsf(bp[t]), fabsf(bp[t + 256])));
        m = fmaxf(m, fmaxf(fabsf(bn[t]), fabsf(bn[t + 256])));
    }
    #pragma unroll
    for (int off = 32; off > 0; off >>= 1)
        m = fmaxf(m, __shfl_xor(m, off, 64));
    __shared__ float wred[4];
    const int wid = t >> 6;
    if ((t & 63) == 0) wred[wid] = m;
    __syncthreads();
    if (t == 0)
        maxp[bid] = fmaxf(fmaxf(wred[0], wred[1]), fmaxf(wred[2], wred[3]));
}

__global__ __launch_bounds__(256, 4)
void memristor_main(const float* __restrict__ x,  const float* __restrict__ wp,
                    const float* __restrict__ wn, const float* __restrict__ bp,
                    const float* __restrict__ bn, const float* __restrict__ nn,
                    const float* __restrict__ maxp, float* __restrict__ y)
{
    __shared__ float4 lsq[CH][17];
    const int jlane = threadIdx.x & 63;
    const int bslot = __builtin_amdgcn_readfirstlane((int)(threadIdx.x >> 6));
    const int bid = blockIdx.x;
    const int jt  = bid & 7;
    const int bt  = (bid >> 3) & 3;
    const int ic  = bid >> 5;
    const int i0 = ic * CH;
    const int j  = jt * 64 + jlane;
    const int b0 = bt * 32;
    {
        const int ii = threadIdx.x & 31;
        const int b8 = threadIdx.x >> 5;
        #pragma unroll
        for (int r = 0; r < 4; ++r) {
            const int bb = b8 + r * 8;
            const float v = x[(b0 + bb) * N_IN + i0 + ii];
            const float s = (v > 0.0f) ? 1.0f : ((v < 0.0f) ? -1.0f : 0.0f);
            const float l = FAST_LOG2(2.0f * fabsf(v));
            reinterpret_cast<float2*>(&lsq[ii][0])[bb] = make_float2(l, s);
        }
    }
    float m = fmaxf(fmaxf(maxp[jlane], maxp[jlane + 64]),
                    fmaxf(maxp[jlane + 128], maxp[jlane + 192]));
    #pragma unroll
    for (int off = 32; off > 0; off >>= 1)
        m = fmaxf(m, __shfl_xor(m, off, 64));
    const float gofs = 0.125f * __uint_as_float(
        __builtin_amdgcn_readfirstlane(__float_as_uint(m)));
    __syncthreads();
    float acc[8];
    #pragma unroll
    for (int k = 0; k < 8; ++k) acc[k] = 0.0f;
    const float*  wprow = wp + (size_t)i0 * N_OUT + j;
    const float*  wnrow = wn + (size_t)i0 * N_OUT + j;
    const float2* nnrow = (const float2*)nn + (size_t)i0 * N_OUT + j;
    #pragma unroll 2
    for (int ii = 0; ii < CH; ++ii) {
        const float wpv  = wprow[ii * N_OUT];
        const float wnv  = wnrow[ii * N_OUT];
        const float2 np2 = nnrow[ii * N_OUT];
        const float ep  = FAST_LOG2(fmaf(0.2f, np2.x, 2.8f));
        const float en  = FAST_LOG2(fmaf(0.2f, np2.y, 2.8f));
        const float lgp = FAST_LOG2(fmaf(0.5f, wpv, gofs));
        const float lgn = FAST_LOG2(fmaf(0.5f, wnv, gofs));
        #pragma unroll
        for (int mm = 0; mm < 4; ++mm) {
            const float4 q = lsq[ii][bslot * 4 + mm];
            const float Ep0 = FAST_EXP2(fmaf(ep, q.x, lgp));
            const float En0 = FAST_EXP2(fmaf(en, q.x, lgn));
            acc[2 * mm]     = fmaf(q.y, Ep0 - En0, acc[2 * mm]);
            const float Ep1 = FAST_EXP2(fmaf(ep, q.z, lgp));
            const float En1 = FAST_EXP2(fmaf(en, q.z, lgn));
            acc[2 * mm + 1] = fmaf(q.w, Ep1 - En1, acc[2 * mm + 1]);
        }
    }
    if (ic == IC - 1) {
        const float2 np2 = ((const float2*)nn)[(size_t)N_IN * N_OUT + j];
        const float npp = fmaf(0.2f, np2.x, 2.8f);
        const float npn = fmaf(0.2f, np2.y, 2.8f);
        const float gp = fmaf(0.5f, bp[j], gofs);
        const float gn = fmaf(0.5f, bn[j], gofs);
        const float t  = fmaf(gp, npp, -(gn * npn));
        #pragma unroll
        for (int k = 0; k < 8; ++k) acc[k] += t;
    }
    #pragma unroll
    for (int k = 0; k < 8; ++k)
        atomicAdd(&y[(b0 + bslot * 8 + k) * N_OUT + j], acc[k]);
}

// ---------------------------------------------------------------------------
extern "C" void kernel_launch(void* const* d_in, const int* in_sizes, int n_in,
                              void* d_out, int out_size, void* d_ws, size_t ws_size,
                              hipStream_t stream)
{
    const float* x  = (const float*)d_in[0];
    const float* wp = (const float*)d_in[1];
    const float* wn = (const float*)d_in[2];
    const float* bp = (const float*)d_in[3];
    const float* bn = (const float*)d_in[4];
    const float* nn = (const float*)d_in[5];
    float*    y    = (float*)d_out;
    unsigned* cnt  = (unsigned*)((char*)d_ws + WS_CNT_OFF);
    float*    maxp = (float*)((char*)d_ws + WS_MAXP_OFF);

    // barrier counter must start at 0 (ws is poisoned to 0xAA)
    (void)hipMemsetAsync(cnt, 0, sizeof(unsigned), stream);

    void* args[] = {(void*)&x, (void*)&wp, (void*)&wn, (void*)&bp, (void*)&bn,
                    (void*)&nn, (void*)&cnt, (void*)&maxp, (void*)&y};
    hipError_t err = hipLaunchCooperativeKernel(
        (const void*)memristor_fused, dim3(NBLK), dim3(256), args, 0, stream);

    if (err != hipSuccess) {
        // fallback: known-good two-kernel path (maxp[256] partials)
        maxred_kernel<<<256, 256, 0, stream>>>((const float4*)wp,
                                               (const float4*)wn, bp, bn,
                                               maxp, y);
        memristor_main<<<NBLK, 256, 0, stream>>>(x, wp, wn, bp, bn, nn,
                                                 maxp, y);
    }
}

// Round 9
// 91.983 us; speedup vs baseline: 2.1967x; 2.1967x over previous
//
#include <hip/hip_runtime.h>

#define N_IN  1024
#define N_OUT 512
#define BATCH 128
#define M     (N_IN + 1)     // 1025 word lines (weights + bias line)

// workspace: maxp[256] floats at offset 0 (per-block max|weights| partials)

// fast base-2 transcendentals: v_exp_f32 / v_log_f32 (both base-2 on AMDGPU)
#if defined(__has_builtin)
#  if __has_builtin(__builtin_amdgcn_exp2f)
#    define FAST_EXP2(x) __builtin_amdgcn_exp2f(x)
#  endif
#  if __has_builtin(__builtin_amdgcn_logf)
#    define FAST_LOG2(x) __builtin_amdgcn_logf(x)
#  endif
#endif
#ifndef FAST_EXP2
#  define FAST_EXP2(x) exp2f(x)
#endif
#ifndef FAST_LOG2
#  define FAST_LOG2(x) log2f(x)
#endif

// ---------------------------------------------------------------------------
// Kernel 1: per-block max|weights| partials -> maxp[256], and zero y.
// 256 blocks x 256 threads. Block 0 also covers the bias vectors.
// ---------------------------------------------------------------------------
__global__ __launch_bounds__(256)
void maxred_kernel(const float4* __restrict__ wp4, const float4* __restrict__ wn4,
                   const float* __restrict__ bp, const float* __restrict__ bn,
                   float* __restrict__ maxp, float* __restrict__ y)
{
    const int bid = blockIdx.x;
    const int t   = threadIdx.x;

    // zero my slice of y (65536 = 256 blocks * 256 threads)
    y[bid * 256 + t] = 0.0f;

    const int base = bid * 512;                  // float4 index; 131072 total
    float m = 0.0f;
    #pragma unroll
    for (int r = 0; r < 2; ++r) {
        const float4 a = wp4[base + r * 256 + t];
        const float4 b = wn4[base + r * 256 + t];
        m = fmaxf(m, fmaxf(fmaxf(fabsf(a.x), fabsf(a.y)),
                           fmaxf(fabsf(a.z), fabsf(a.w))));
        m = fmaxf(m, fmaxf(fmaxf(fabsf(b.x), fabsf(b.y)),
                           fmaxf(fabsf(b.z), fabsf(b.w))));
    }
    if (bid == 0) {
        m = fmaxf(m, fmaxf(fabsf(bp[t]), fabsf(bp[t + 256])));
        m = fmaxf(m, fmaxf(fabsf(bn[t]), fabsf(bn[t + 256])));
    }
    #pragma unroll
    for (int off = 32; off > 0; off >>= 1)
        m = fmaxf(m, __shfl_xor(m, off, 64));

    __shared__ float wred[4];
    const int wid = t >> 6;
    if ((t & 63) == 0) wred[wid] = m;
    __syncthreads();
    if (t == 0)
        maxp[bid] = fmaxf(fmaxf(wred[0], wred[1]), fmaxf(wred[2], wred[3]));
}

// ---------------------------------------------------------------------------
// Kernel 2: fused main compute.
//   y[b,j] += s * ( exp2(fma(ep,l,lgp)) - exp2(fma(en,l,lgn)) )
//   lgp/lgn = log2(0.5*w + 0.125*maxw) ; ep/en = log2(2.8 + 0.2*noise)
//   l = log2(2|x|), s = sign(x).  x==0 -> l=-inf -> both exp2 = 0.
// Block: 256 thr = 64 j-lanes x 4 waves; each wave owns 8 batches.
// Grid: 8 jt x 4 bt x 32 ic (32 rows each) = 1024 blocks (4/CU, 16 waves/CU).
// LDS: float4 pairs (l0,s0,l1,s1) read b128-wide at wave-uniform addresses.
// Bias word line (i=1024) is a closed-form epilogue on ic==31.
// ---------------------------------------------------------------------------
#define CH 32
#define IC 32

__global__ __launch_bounds__(256, 4)
void memristor_main(const float* __restrict__ x,  const float* __restrict__ wp,
                    const float* __restrict__ wn, const float* __restrict__ bp,
                    const float* __restrict__ bn, const float* __restrict__ nn,
                    const float* __restrict__ maxp, float* __restrict__ y)
{
    // [row ii][batch-pair 0..15, +1 pad] ; pair p = batches (2p, 2p+1)
    __shared__ float4 lsq[CH][17];

    const int jlane = threadIdx.x & 63;
    const int bslot = __builtin_amdgcn_readfirstlane((int)(threadIdx.x >> 6));

    const int bid = blockIdx.x;
    const int jt  = bid & 7;
    const int bt  = (bid >> 3) & 3;
    const int ic  = bid >> 5;                    // 0..31

    const int i0 = ic * CH;
    const int j  = jt * 64 + jlane;
    const int b0 = bt * 32;

    // ---- stage (l = log2(2|x|), s = sign) for 32 batches x 32 rows ----
    {
        const int ii = threadIdx.x & 31;         // row in chunk (coalesced x)
        const int b8 = threadIdx.x >> 5;         // 0..7
        #pragma unroll
        for (int r = 0; r < 4; ++r) {
            const int bb = b8 + r * 8;           // batch in tile
            const float v = x[(b0 + bb) * N_IN + i0 + ii];
            const float s = (v > 0.0f) ? 1.0f : ((v < 0.0f) ? -1.0f : 0.0f);
            const float l = FAST_LOG2(2.0f * fabsf(v));
            reinterpret_cast<float2*>(&lsq[ii][0])[bb] = make_float2(l, s);
        }
    }

    // ---- global max|w| from the 256 partials (wave-local reduce) ----
    float m = fmaxf(fmaxf(maxp[jlane], maxp[jlane + 64]),
                    fmaxf(maxp[jlane + 128], maxp[jlane + 192]));
    #pragma unroll
    for (int off = 32; off > 0; off >>= 1)
        m = fmaxf(m, __shfl_xor(m, off, 64));
    const float gofs = 0.125f * __uint_as_float(
        __builtin_amdgcn_readfirstlane(__float_as_uint(m)));

    __syncthreads();

    float acc[8];
    #pragma unroll
    for (int k = 0; k < 8; ++k) acc[k] = 0.0f;

    const float*  wprow = wp + (size_t)i0 * N_OUT + j;
    const float*  wnrow = wn + (size_t)i0 * N_OUT + j;
    const float2* nnrow = (const float2*)nn + (size_t)i0 * N_OUT + j;

    #pragma unroll 2
    for (int ii = 0; ii < CH; ++ii) {
        const float wpv  = wprow[ii * N_OUT];
        const float wnv  = wnrow[ii * N_OUT];
        const float2 np2 = nnrow[ii * N_OUT];
        const float ep  = FAST_LOG2(fmaf(0.2f, np2.x, 2.8f));
        const float en  = FAST_LOG2(fmaf(0.2f, np2.y, 2.8f));
        const float lgp = FAST_LOG2(fmaf(0.5f, wpv, gofs));
        const float lgn = FAST_LOG2(fmaf(0.5f, wnv, gofs));
        #pragma unroll
        for (int mm = 0; mm < 4; ++mm) {
            const float4 q = lsq[ii][bslot * 4 + mm];   // uniform addr: broadcast
            const float Ep0 = FAST_EXP2(fmaf(ep, q.x, lgp));
            const float En0 = FAST_EXP2(fmaf(en, q.x, lgn));
            acc[2 * mm]     = fmaf(q.y, Ep0 - En0, acc[2 * mm]);
            const float Ep1 = FAST_EXP2(fmaf(ep, q.z, lgp));
            const float En1 = FAST_EXP2(fmaf(en, q.z, lgn));
            acc[2 * mm + 1] = fmaf(q.w, Ep1 - En1, acc[2 * mm + 1]);
        }
    }

    // ---- bias word line (i = N_IN): l = 1, s = 1 -> g * n exactly ----
    if (ic == IC - 1) {
        const float2 np2 = ((const float2*)nn)[(size_t)N_IN * N_OUT + j];
        const float npp = fmaf(0.2f, np2.x, 2.8f);
        const float npn = fmaf(0.2f, np2.y, 2.8f);
        const float gp = fmaf(0.5f, bp[j], gofs);
        const float gn = fmaf(0.5f, bn[j], gofs);
        const float t  = fmaf(gp, npp, -(gn * npn));
        #pragma unroll
        for (int k = 0; k < 8; ++k) acc[k] += t;
    }

    #pragma unroll
    for (int k = 0; k < 8; ++k)
        atomicAdd(&y[(b0 + bslot * 8 + k) * N_OUT + j], acc[k]);
}

// ---------------------------------------------------------------------------
extern "C" void kernel_launch(void* const* d_in, const int* in_sizes, int n_in,
                              void* d_out, int out_size, void* d_ws, size_t ws_size,
                              hipStream_t stream)
{
    const float* x  = (const float*)d_in[0];
    const float* wp = (const float*)d_in[1];
    const float* wn = (const float*)d_in[2];
    const float* bp = (const float*)d_in[3];
    const float* bn = (const float*)d_in[4];
    const float* nn = (const float*)d_in[5];
    float* y        = (float*)d_out;
    float* maxp     = (float*)d_ws;

    maxred_kernel<<<256, 256, 0, stream>>>((const float4*)wp, (const float4*)wn,
                                           bp, bn, maxp, y);

    memristor_main<<<8 * 4 * IC, 256, 0, stream>>>(x, wp, wn, bp, bn, nn,
                                                   maxp, y);
}